// Round 9
// baseline (341.710 us; speedup 1.0000x reference)
//
#include <hip/hip_runtime.h>
#include <stdint.h>

#define D_MODEL 768
#define N3      2304
#define NHEAD   8
#define DH      96
#define BATCH   8
#define SEQ     4096
#define ROWS    (BATCH*SEQ)   // 32768
#define LN_EPS  1e-5f

typedef __attribute__((ext_vector_type(8))) __bf16 bf16x8;
typedef __attribute__((ext_vector_type(4))) float f32x4;
typedef __attribute__((ext_vector_type(16))) float f32x16;
typedef __attribute__((ext_vector_type(8))) unsigned short ushort8;
typedef __attribute__((ext_vector_type(4))) unsigned short ushort4v;

__device__ __forceinline__ unsigned short f2bf(float f) {
  union { float f; unsigned int u; } v; v.f = f;
  unsigned int r = v.u + 0x7FFFu + ((v.u >> 16) & 1u);
  return (unsigned short)(r >> 16);
}
__device__ __forceinline__ float bf2f(unsigned short u) {
  union { unsigned int u; float f; } v; v.u = ((unsigned int)u) << 16;
  return v.f;
}

#define GLOBAL_LDS16(src, dst) \
  __builtin_amdgcn_global_load_lds((const __attribute__((address_space(1))) void*)(src), \
                                   (__attribute__((address_space(3))) void*)(dst), 16, 0, 0)

#define GATE(n) do { asm volatile("s_waitcnt vmcnt(" #n ")" ::: "memory"); \
                     __builtin_amdgcn_s_barrier(); asm volatile("" ::: "memory"); } while (0)

// ---------------- transpose + cast fp32[R][C] -> bf16[C][R] ----------------
__global__ __launch_bounds__(256) void transpose_cast_kernel(
    const float* __restrict__ in, unsigned short* __restrict__ out, int R, int C) {
  __shared__ float tile[32][33];
  int c0 = blockIdx.x * 32, r0 = blockIdx.y * 32;
  int tx = threadIdx.x & 31, ty = threadIdx.x >> 5;
  #pragma unroll
  for (int i = ty; i < 32; i += 8)
    tile[i][tx] = in[(size_t)(r0 + i) * C + c0 + tx];
  __syncthreads();
  #pragma unroll
  for (int i = ty; i < 32; i += 8)
    out[(size_t)(c0 + i) * R + r0 + tx] = f2bf(tile[tx][i]);
}

// ---------------- LayerNorm: fp32 in -> bf16 out, one wave per row ----------------
__global__ __launch_bounds__(256) void ln_kernel(
    const float* __restrict__ x, const float* __restrict__ gamma,
    const float* __restrict__ beta, unsigned short* __restrict__ xn) {
  int wave = threadIdx.x >> 6, lane = threadIdx.x & 63;
  int row = blockIdx.x * 4 + wave;
  const float* xr = x + (size_t)row * D_MODEL;
  f32x4 v[3];
  float s = 0.f, sq = 0.f;
  #pragma unroll
  for (int i = 0; i < 3; ++i) {
    v[i] = *(const f32x4*)(xr + (i * 64 + lane) * 4);
    #pragma unroll
    for (int c = 0; c < 4; ++c) { s += v[i][c]; sq += v[i][c] * v[i][c]; }
  }
  #pragma unroll
  for (int o = 32; o; o >>= 1) {
    s  += __shfl_xor(s, o, 64);
    sq += __shfl_xor(sq, o, 64);
  }
  float mu  = s * (1.f / 768.f);
  float var = sq * (1.f / 768.f) - mu * mu;
  float rs  = rsqrtf(var + LN_EPS);
  #pragma unroll
  for (int i = 0; i < 3; ++i) {
    int col = (i * 64 + lane) * 4;
    ushort4v o;
    #pragma unroll
    for (int c = 0; c < 4; ++c)
      o[c] = f2bf((v[i][c] - mu) * rs * gamma[col + c] + beta[col + c]);
    *(ushort4v*)(xn + (size_t)row * D_MODEL + col) = o;
  }
}

// ====== qkv GEMM 128x128, BK=32, 3 bufs, 3 blocks/CU, 32x32x16 MFMA ======
// C = A[32768][768] @ Bt[2304][768]^T. 4 waves (2x2), per-wave out 64x64.
// bn 0..5 -> Q row-major (elu+1); 6..11 -> K; 12..17 -> V, K/V in BLOCKED
// transposed layout [lblk=bm (256)][h][d][l 128] (addr (bm*8+h)*96+d)*128+ll).
// 32x32x16 frags: A/B lane l: row/col=l&31, k=(l>>5)*8+j; C: col=l&31,
// row=(reg&3)+8*(reg>>2)+4*(l>>5). Swizzle: phys slot = logical ^ ((l>>1)&3).
__global__ __launch_bounds__(256, 3) void gemm_qkv128_kernel(
    const unsigned short* __restrict__ A, const unsigned short* __restrict__ Bt,
    unsigned short* __restrict__ qb, unsigned short* __restrict__ kT,
    unsigned short* __restrict__ vT) {
  __shared__ unsigned short As[3 * 4096];  // [buf][128][32]
  __shared__ unsigned short Bs[3 * 4096];
  const int K = D_MODEL, nbn = 18;
  int nwg = gridDim.x, id = blockIdx.x;
  int q8 = nwg >> 3;
  int wg = (id & 7) * q8 + (id >> 3);
  int bm = wg / nbn, bn = wg % nbn;

  const int lane = threadIdx.x & 63, wid = threadIdx.x >> 6;
  const int wm = wid >> 1, wn = wid & 1;
  const int l31 = lane & 31, l5 = lane >> 5;
  const int sx0 = (l5 ^ ((lane >> 1) & 3)) << 3;        // kh=0 slot (shorts)
  const int sx1 = ((2 + l5) ^ ((lane >> 1) & 3)) << 3;  // kh=1
  const int srow = lane >> 2;
  const int scol = ((lane & 3) ^ ((lane >> 3) & 3)) << 3;

  const unsigned short* a0 = A  + (size_t)(bm * 128 +      wid * 16 + srow) * K + scol;
  const unsigned short* a1 = A  + (size_t)(bm * 128 + 64 + wid * 16 + srow) * K + scol;
  const unsigned short* b0 = Bt + (size_t)(bn * 128 +      wid * 16 + srow) * K + scol;
  const unsigned short* b1 = Bt + (size_t)(bn * 128 + 64 + wid * 16 + srow) * K + scol;
  auto stage = [&](int buf, int kt) {
    GLOBAL_LDS16(a0 + kt * 32, &As[buf * 4096 +        wid * 512]);
    GLOBAL_LDS16(a1 + kt * 32, &As[buf * 4096 + 2048 + wid * 512]);
    GLOBAL_LDS16(b0 + kt * 32, &Bs[buf * 4096 +        wid * 512]);
    GLOBAL_LDS16(b1 + kt * 32, &Bs[buf * 4096 + 2048 + wid * 512]);
  };

  f32x16 acc[2][2];
  #pragma unroll
  for (int i = 0; i < 2; ++i)
    #pragma unroll
    for (int j = 0; j < 2; ++j)
      #pragma unroll
      for (int r = 0; r < 16; ++r) acc[i][j][r] = 0.f;

#define QTILE(BUF, STG) do { \
    bf16x8 af[2][2], bv[2][2]; \
    _Pragma("unroll") for (int mf = 0; mf < 2; ++mf) { \
      int rb = (BUF) * 4096 + (wm * 64 + mf * 32 + l31) * 32; \
      af[mf][0] = *(const bf16x8*)&As[rb + sx0]; \
      af[mf][1] = *(const bf16x8*)&As[rb + sx1]; } \
    _Pragma("unroll") for (int nf = 0; nf < 2; ++nf) { \
      int rb = (BUF) * 4096 + (wn * 64 + nf * 32 + l31) * 32; \
      bv[nf][0] = *(const bf16x8*)&Bs[rb + sx0]; \
      bv[nf][1] = *(const bf16x8*)&Bs[rb + sx1]; } \
    STG; \
    __builtin_amdgcn_s_setprio(1); \
    _Pragma("unroll") for (int mf = 0; mf < 2; ++mf) \
      _Pragma("unroll") for (int nf = 0; nf < 2; ++nf) { \
        acc[mf][nf] = __builtin_amdgcn_mfma_f32_32x32x16_bf16( \
            af[mf][0], bv[nf][0], acc[mf][nf], 0, 0, 0); \
        acc[mf][nf] = __builtin_amdgcn_mfma_f32_32x32x16_bf16( \
            af[mf][1], bv[nf][1], acc[mf][nf], 0, 0, 0); } \
    __builtin_amdgcn_s_setprio(0); \
  } while (0)

  stage(0, 0); stage(1, 1);
  for (int it = 0; it < 7; ++it) {
    int T = 3 * it;
    GATE(4); QTILE(0, stage(2, T + 2));
    GATE(4); QTILE(1, stage(0, T + 3));
    GATE(4); QTILE(2, stage(1, T + 4));
  }
  GATE(4); QTILE(0, stage(2, 23));
  GATE(4); QTILE(1, {});
  GATE(0); QTILE(2, {});
#undef QTILE

  // Epilogue: block-uniform Q / K / V routing (32x32 C layout)
  int r0 = bm * 128 + wm * 64, c0 = bn * 128 + wn * 64;
  if (bn < 6) {
    #pragma unroll
    for (int mf = 0; mf < 2; ++mf)
      #pragma unroll
      for (int nf = 0; nf < 2; ++nf) {
        int col = c0 + nf * 32 + l31;
        #pragma unroll
        for (int r = 0; r < 16; ++r) {
          int row = r0 + mf * 32 + (r & 3) + 8 * (r >> 2) + 4 * l5;
          float v = acc[mf][nf][r];
          v = (v > 0.f) ? v + 1.f : __expf(v);          // elu(x)+1
          qb[(size_t)row * D_MODEL + col] = f2bf(v);
        }
      }
  } else {
    const bool isK = (bn < 12);
    unsigned short* T = isK ? kT : vT;
    int cbase = c0 - (isK ? 768 : 1536);
    #pragma unroll
    for (int mf = 0; mf < 2; ++mf)
      #pragma unroll
      for (int nf = 0; nf < 2; ++nf) {
        int cc = cbase + nf * 32 + l31;
        int h = cc / 96, d = cc - h * 96;
        size_t rowb = (((size_t)bm * 8 + h) * 96 + d) * 128;
        #pragma unroll
        for (int rq = 0; rq < 4; ++rq) {
          int ll = wm * 64 + mf * 32 + 8 * rq + 4 * l5;  // local l (of 128)
          ushort4v pk;
          #pragma unroll
          for (int j = 0; j < 4; ++j) {
            float v = acc[mf][nf][rq * 4 + j];
            if (isK) v = (v > 0.f) ? v + 1.f : __expf(v);  // elu(x)+1
            pk[j] = f2bf(v);
          }
          *(ushort4v*)&T[rowb + ll] = pk;
        }
      }
  }
}

// ======== out GEMM 128x128, BK=32, 3 bufs, 3 blocks/CU, 32x32x16 MFMA ========
__global__ __launch_bounds__(256, 3) void gemm_out_kernel(
    const unsigned short* __restrict__ A, const unsigned short* __restrict__ Bt,
    const float* __restrict__ resid, float* __restrict__ Cf) {
  __shared__ unsigned short As[3 * 4096];  // [buf][128][32]
  __shared__ unsigned short Bs[3 * 4096];
  const int K = D_MODEL, nbn = 6;          // N=768
  int nwg = gridDim.x, id = blockIdx.x;
  int q8 = nwg >> 3;
  int wg = (id & 7) * q8 + (id >> 3);
  int bm = wg / nbn, bn = wg % nbn;

  const int lane = threadIdx.x & 63, wid = threadIdx.x >> 6;
  const int wm = wid >> 1, wn = wid & 1;
  const int l31 = lane & 31, l5 = lane >> 5;
  const int sx0 = (l5 ^ ((lane >> 1) & 3)) << 3;
  const int sx1 = ((2 + l5) ^ ((lane >> 1) & 3)) << 3;
  const int srow = lane >> 2;
  const int scol = ((lane & 3) ^ ((lane >> 3) & 3)) << 3;

  const unsigned short* a0 = A  + (size_t)(bm * 128 +      wid * 16 + srow) * K + scol;
  const unsigned short* a1 = A  + (size_t)(bm * 128 + 64 + wid * 16 + srow) * K + scol;
  const unsigned short* b0 = Bt + (size_t)(bn * 128 +      wid * 16 + srow) * K + scol;
  const unsigned short* b1 = Bt + (size_t)(bn * 128 + 64 + wid * 16 + srow) * K + scol;
  auto stage = [&](int buf, int kt) {
    GLOBAL_LDS16(a0 + kt * 32, &As[buf * 4096 +        wid * 512]);
    GLOBAL_LDS16(a1 + kt * 32, &As[buf * 4096 + 2048 + wid * 512]);
    GLOBAL_LDS16(b0 + kt * 32, &Bs[buf * 4096 +        wid * 512]);
    GLOBAL_LDS16(b1 + kt * 32, &Bs[buf * 4096 + 2048 + wid * 512]);
  };

  f32x16 acc[2][2];
  #pragma unroll
  for (int i = 0; i < 2; ++i)
    #pragma unroll
    for (int j = 0; j < 2; ++j)
      #pragma unroll
      for (int r = 0; r < 16; ++r) acc[i][j][r] = 0.f;

#define HTILE(BUF, STG) do { \
    bf16x8 af[2][2], bv[2][2]; \
    _Pragma("unroll") for (int mf = 0; mf < 2; ++mf) { \
      int rb = (BUF) * 4096 + (wm * 64 + mf * 32 + l31) * 32; \
      af[mf][0] = *(const bf16x8*)&As[rb + sx0]; \
      af[mf][1] = *(const bf16x8*)&As[rb + sx1]; } \
    _Pragma("unroll") for (int nf = 0; nf < 2; ++nf) { \
      int rb = (BUF) * 4096 + (wn * 64 + nf * 32 + l31) * 32; \
      bv[nf][0] = *(const bf16x8*)&Bs[rb + sx0]; \
      bv[nf][1] = *(const bf16x8*)&Bs[rb + sx1]; } \
    STG; \
    __builtin_amdgcn_s_setprio(1); \
    _Pragma("unroll") for (int mf = 0; mf < 2; ++mf) \
      _Pragma("unroll") for (int nf = 0; nf < 2; ++nf) { \
        acc[mf][nf] = __builtin_amdgcn_mfma_f32_32x32x16_bf16( \
            af[mf][0], bv[nf][0], acc[mf][nf], 0, 0, 0); \
        acc[mf][nf] = __builtin_amdgcn_mfma_f32_32x32x16_bf16( \
            af[mf][1], bv[nf][1], acc[mf][nf], 0, 0, 0); } \
    __builtin_amdgcn_s_setprio(0); \
  } while (0)

  stage(0, 0); stage(1, 1);
  for (int it = 0; it < 7; ++it) {
    int T = 3 * it;
    GATE(4); HTILE(0, stage(2, T + 2));
    GATE(4); HTILE(1, stage(0, T + 3));
    GATE(4); HTILE(2, stage(1, T + 4));
  }
  GATE(4); HTILE(0, stage(2, 23));
  GATE(4); HTILE(1, {});
  GATE(0); HTILE(2, {});
#undef HTILE

  int r0 = bm * 128 + wm * 64, c0 = bn * 128 + wn * 64;
  #pragma unroll
  for (int mf = 0; mf < 2; ++mf)
    #pragma unroll
    for (int nf = 0; nf < 2; ++nf) {
      int col = c0 + nf * 32 + l31;
      #pragma unroll
      for (int r = 0; r < 16; ++r) {
        int row = r0 + mf * 32 + (r & 3) + 8 * (r >> 2) + 4 * l5;
        Cf[(size_t)row * D_MODEL + col] =
            acc[mf][nf][r] + resid[(size_t)row * D_MODEL + col];
      }
    }
}

// ======== kv aggregation: blocked kT/vT staging + phantom ones-row ======
__global__ __launch_bounds__(256) void kvagg2_kernel(
    const unsigned short* __restrict__ kT, const unsigned short* __restrict__ vT,
    float* __restrict__ kvp) {
  __shared__ unsigned short KTs[3 * 6144];   // [buf][96][64]
  __shared__ unsigned short VTs[3 * 8192];   // [buf][128][64]
  int bh = blockIdx.x >> 2, chunk = blockIdx.x & 3;
  int tid = threadIdx.x;
  int lane = tid & 63, wid = tid >> 6;
  int l15 = lane & 15, hi = lane >> 4;

  #pragma unroll
  for (int i = 0; i < 3; ++i) {
    int s = i * 256 + tid;
    int buf = s >> 8, r = 96 + ((s >> 3) & 31), sl = s & 7;
    unsigned short val = (r == 96) ? (unsigned short)0x3F80 : (unsigned short)0;
    ushort8 v8 = {val, val, val, val, val, val, val, val};
    *(ushort8*)&VTs[buf * 8192 + r * 64 + sl * 8] = v8;
  }
  __syncthreads();

  const int b = bh >> 3, h = bh & 7;
  auto stage = [&](int buf, int t) {
    #pragma unroll
    for (int i = 0; i < 3; ++i) {
      int sidx = i * 256 + tid;
      int row = sidx >> 3;                        // d
      int L = (sidx & 7) ^ (row & 7);
      size_t g = ((((size_t)b * 32 + chunk * 8 + (t >> 1)) * 8 + h) * 96 + row) * 128
               + (t & 1) * 64 + L * 8;
      GLOBAL_LDS16(kT + g, &KTs[buf * 6144 + (i * 256 + wid * 64) * 8]);
      GLOBAL_LDS16(vT + g, &VTs[buf * 8192 + (i * 256 + wid * 64) * 8]);
    }
  };

  f32x4 acc[6][2];
  #pragma unroll
  for (int i = 0; i < 6; ++i)
    #pragma unroll
    for (int j = 0; j < 2; ++j) acc[i][j] = (f32x4){0.f, 0.f, 0.f, 0.f};

#define KVTILE(BUF) do { \
    _Pragma("unroll") for (int kq = 0; kq < 2; ++kq) { \
      bf16x8 af[6], bv[2]; \
      _Pragma("unroll") for (int mf = 0; mf < 6; ++mf) { \
        int row = mf * 16 + l15; \
        af[mf] = *(const bf16x8*)&KTs[(BUF) * 6144 + row * 64 + ((kq * 4 + hi) ^ (row & 7)) * 8]; } \
      _Pragma("unroll") for (int nf = 0; nf < 2; ++nf) { \
        int row = wid * 32 + nf * 16 + l15; \
        bv[nf] = *(const bf16x8*)&VTs[(BUF) * 8192 + row * 64 + ((kq * 4 + hi) ^ (row & 7)) * 8]; } \
      __builtin_amdgcn_s_setprio(1); \
      _Pragma("unroll") for (int mf = 0; mf < 6; ++mf) \
        _Pragma("unroll") for (int nf = 0; nf < 2; ++nf) \
          acc[mf][nf] = __builtin_amdgcn_mfma_f32_16x16x32_bf16( \
              af[mf], bv[nf], acc[mf][nf], 0, 0, 0); \
      __builtin_amdgcn_s_setprio(0); \
    } } while (0)

  stage(0, 0); stage(1, 1);
  for (int t = 0; t < 14; ++t) {
    stage((t + 2) % 3, t + 2);
    GATE(12);
    KVTILE(t % 3);
  }
  GATE(6); KVTILE(2);
  GATE(0); KVTILE(0);
#undef KVTILE

  float* outp = kvp + ((size_t)bh * 4 + chunk) * (96 * 112);
  #pragma unroll
  for (int nf = 0; nf < 2; ++nf) {
    int e = wid * 32 + nf * 16 + l15;
    if (e < 112) {
      #pragma unroll
      for (int mf = 0; mf < 6; ++mf)
        #pragma unroll
        for (int r = 0; r < 4; ++r) {
          int d = mf * 16 + hi * 4 + r;
          outp[d * 112 + e] = acc[mf][nf][r];
        }
    }
  }
}

// ---------------- reduce 4 partials -> kvT bf16 [64][112][96] ----------------
__global__ __launch_bounds__(256) void kvreduce_kernel(
    const float* __restrict__ kvp, unsigned short* __restrict__ kvTo) {
  int idx = blockIdx.x * 256 + threadIdx.x;
  if (idx >= 64 * 112 * 96) return;
  int d = idx % 96;
  int e = (idx / 96) % 112;
  int bh = idx / (96 * 112);
  float s = 0.f;
  #pragma unroll
  for (int c = 0; c < 4; ++c)
    s += kvp[(((size_t)bh * 4 + c) * 96 + d) * 112 + e];
  kvTo[idx] = f2bf(s);
}

// ---------------- readout: q row-major in qb [32768][768] ----------------
__global__ __launch_bounds__(256) void readout_kernel(
    const unsigned short* __restrict__ qb, const unsigned short* __restrict__ kvT,
    unsigned short* __restrict__ attn) {
  __shared__ unsigned short Qs[128][104];
  __shared__ unsigned short Ks[112][104];
  int bh = blockIdx.x >> 5, lc = blockIdx.x & 31;
  int b = bh >> 3, h = bh & 7;
  int l0 = lc * 128;
  int wave = threadIdx.x >> 6, lane = threadIdx.x & 63;
  #pragma unroll
  for (int i = 0; i < 6; ++i) {
    int idx = i * 256 + threadIdx.x;
    int l = idx / 12, oc = idx % 12;
    size_t g = ((size_t)b * SEQ + l0 + l) * D_MODEL + h * DH + oc * 8;
    *(ushort8*)&Qs[l][oc * 8] = *(const ushort8*)(qb + g);
  }
  const unsigned short* kvbh = kvT + (size_t)bh * 112 * 96;
  #pragma unroll
  for (int i = 0; i < 6; ++i) {
    int idx = i * 256 + threadIdx.x;
    if (idx < 1344) {
      int e = idx / 12, oc = idx % 12;
      *(ushort8*)&Ks[e][oc * 8] = *(const ushort8*)(kvbh + e * 96 + oc * 8);
    }
  }
  __syncthreads();
  f32x4 acc[2][7];
  #pragma unroll
  for (int i = 0; i < 2; ++i)
    #pragma unroll
    for (int j = 0; j < 7; ++j) acc[i][j] = (f32x4){0.f, 0.f, 0.f, 0.f};
  #pragma unroll
  for (int kq = 0; kq < 3; ++kq) {
    int k0 = kq * 32 + (lane >> 4) * 8;
    bf16x8 af[2], bfv[7];
    #pragma unroll
    for (int i = 0; i < 2; ++i) af[i]  = *(const bf16x8*)&Qs[wave * 32 + i * 16 + (lane & 15)][k0];
    #pragma unroll
    for (int j = 0; j < 7; ++j) bfv[j] = *(const bf16x8*)&Ks[j * 16 + (lane & 15)][k0];
    #pragma unroll
    for (int i = 0; i < 2; ++i)
      #pragma unroll
      for (int j = 0; j < 7; ++j)
        acc[i][j] = __builtin_amdgcn_mfma_f32_16x16x32_bf16(af[i], bfv[j], acc[i][j], 0, 0, 0);
  }
  int g4 = lane >> 4;
  #pragma unroll
  for (int i = 0; i < 2; ++i) {
    #pragma unroll
    for (int r = 0; r < 4; ++r) {
      float nv = __shfl(acc[i][6][r], lane & 48, 64);   // col 96 = normalizer
      float inv = 1.f / fmaxf(nv, 1e-6f);
      size_t orow = (size_t)b * SEQ + l0 + wave * 32 + i * 16 + g4 * 4 + r;
      #pragma unroll
      for (int j = 0; j < 6; ++j) {
        int col = h * DH + j * 16 + (lane & 15);
        attn[orow * D_MODEL + col] = f2bf(acc[i][j][r] * inv);
      }
    }
  }
}

extern "C" void kernel_launch(void* const* d_in, const int* in_sizes, int n_in,
                              void* d_out, int out_size, void* d_ws, size_t ws_size,
                              hipStream_t stream) {
  const float* x     = (const float*)d_in[0];
  const float* gamma = (const float*)d_in[1];
  const float* beta  = (const float*)d_in[2];
  const float* w_qkv = (const float*)d_in[3];
  const float* w_out = (const float*)d_in[4];
  float* out = (float*)d_out;

  char* ws = (char*)d_ws;
  size_t off = 0;
  auto alloc = [&](size_t bytes) -> void* {
    void* p = ws + off; off += (bytes + 255) & ~(size_t)255; return p;
  };
  unsigned short* xn    = (unsigned short*)alloc((size_t)ROWS * D_MODEL * 2);  // reused as attn
  unsigned short* qb    = (unsigned short*)alloc((size_t)ROWS * D_MODEL * 2);
  unsigned short* kTb   = (unsigned short*)alloc((size_t)64 * 96 * SEQ * 2);
  unsigned short* vTb   = (unsigned short*)alloc((size_t)64 * 96 * SEQ * 2);
  unsigned short* wqkvT = (unsigned short*)alloc((size_t)N3 * D_MODEL * 2);
  unsigned short* woutT = (unsigned short*)alloc((size_t)D_MODEL * D_MODEL * 2);
  float* kvp            = (float*)alloc((size_t)256 * 96 * 112 * 4);
  unsigned short* kvT   = (unsigned short*)alloc((size_t)64 * 112 * 96 * 2);

  transpose_cast_kernel<<<dim3(N3 / 32, D_MODEL / 32), 256, 0, stream>>>(w_qkv, wqkvT, D_MODEL, N3);
  transpose_cast_kernel<<<dim3(D_MODEL / 32, D_MODEL / 32), 256, 0, stream>>>(w_out, woutT, D_MODEL, D_MODEL);
  ln_kernel<<<ROWS / 4, 256, 0, stream>>>(x, gamma, beta, xn);
  gemm_qkv128_kernel<<<(ROWS / 128) * (N3 / 128), 256, 0, stream>>>(xn, wqkvT, qb, kTb, vTb);
  kvagg2_kernel<<<256, 256, 0, stream>>>(kTb, vTb, kvp);
  kvreduce_kernel<<<(64 * 112 * 96 + 255) / 256, 256, 0, stream>>>(kvp, kvT);
  readout_kernel<<<2048, 256, 0, stream>>>(qb, kvT, xn);  // attn overwrites xn
  gemm_out_kernel<<<(ROWS / 128) * (D_MODEL / 128), 256, 0, stream>>>(xn, woutT, x, out);
}

// Round 10
// 327.913 us; speedup vs baseline: 1.0421x; 1.0421x over previous
//
#include <hip/hip_runtime.h>
#include <stdint.h>

#define D_MODEL 768
#define N3      2304
#define NHEAD   8
#define DH      96
#define BATCH   8
#define SEQ     4096
#define ROWS    (BATCH*SEQ)   // 32768
#define LN_EPS  1e-5f

typedef __attribute__((ext_vector_type(8))) __bf16 bf16x8;
typedef __attribute__((ext_vector_type(4))) float f32x4;
typedef __attribute__((ext_vector_type(8))) unsigned short ushort8;
typedef __attribute__((ext_vector_type(4))) unsigned short ushort4v;

__device__ __forceinline__ unsigned short f2bf(float f) {
  union { float f; unsigned int u; } v; v.f = f;
  unsigned int r = v.u + 0x7FFFu + ((v.u >> 16) & 1u);
  return (unsigned short)(r >> 16);
}
__device__ __forceinline__ float bf2f(unsigned short u) {
  union { unsigned int u; float f; } v; v.u = ((unsigned int)u) << 16;
  return v.f;
}

#define GLOBAL_LDS16(src, dst) \
  __builtin_amdgcn_global_load_lds((const __attribute__((address_space(1))) void*)(src), \
                                   (__attribute__((address_space(3))) void*)(dst), 16, 0, 0)

#define GATE(n) do { asm volatile("s_waitcnt vmcnt(" #n ")" ::: "memory"); \
                     __builtin_amdgcn_s_barrier(); asm volatile("" ::: "memory"); } while (0)
// Pipelined gate: also drains lgkm so ALL waves' prior ds_reads have executed
// after the barrier (makes staging into a previously-read buffer safe).
#define GATEP(n) do { asm volatile("s_waitcnt vmcnt(" #n ") lgkmcnt(0)" ::: "memory"); \
                      __builtin_amdgcn_s_barrier(); asm volatile("" ::: "memory"); } while (0)

// ---------------- merged transpose + cast fp32[R][C] -> bf16[C][R] ----------------
// bx < 72: w_qkv (768 x 2304); else: w_out (768 x 768)
__global__ __launch_bounds__(256) void transpose2_kernel(
    const float* __restrict__ wqkv, const float* __restrict__ wout,
    unsigned short* __restrict__ wqkvT, unsigned short* __restrict__ woutT) {
  __shared__ float tile[32][33];
  int bx = blockIdx.x;
  const float* in; unsigned short* out; int C, c0;
  if (bx < 72) { in = wqkv; out = wqkvT; C = N3;      c0 = bx * 32; }
  else         { in = wout; out = woutT; C = D_MODEL; c0 = (bx - 72) * 32; }
  int r0 = blockIdx.y * 32;
  int tx = threadIdx.x & 31, ty = threadIdx.x >> 5;
  #pragma unroll
  for (int i = ty; i < 32; i += 8)
    tile[i][tx] = in[(size_t)(r0 + i) * C + c0 + tx];
  __syncthreads();
  #pragma unroll
  for (int i = ty; i < 32; i += 8)
    out[(size_t)(c0 + i) * D_MODEL + r0 + tx] = f2bf(tile[tx][i]);
}

// ---------------- LayerNorm: fp32 in -> bf16 out, one wave per row ----------------
__global__ __launch_bounds__(256) void ln_kernel(
    const float* __restrict__ x, const float* __restrict__ gamma,
    const float* __restrict__ beta, unsigned short* __restrict__ xn) {
  int wave = threadIdx.x >> 6, lane = threadIdx.x & 63;
  int row = blockIdx.x * 4 + wave;
  const float* xr = x + (size_t)row * D_MODEL;
  f32x4 v[3];
  float s = 0.f, sq = 0.f;
  #pragma unroll
  for (int i = 0; i < 3; ++i) {
    v[i] = *(const f32x4*)(xr + (i * 64 + lane) * 4);
    #pragma unroll
    for (int c = 0; c < 4; ++c) { s += v[i][c]; sq += v[i][c] * v[i][c]; }
  }
  #pragma unroll
  for (int o = 32; o; o >>= 1) {
    s  += __shfl_xor(s, o, 64);
    sq += __shfl_xor(sq, o, 64);
  }
  float mu  = s * (1.f / 768.f);
  float var = sq * (1.f / 768.f) - mu * mu;
  float rs  = rsqrtf(var + LN_EPS);
  #pragma unroll
  for (int i = 0; i < 3; ++i) {
    int col = (i * 64 + lane) * 4;
    ushort4v o;
    #pragma unroll
    for (int c = 0; c < 4; ++c)
      o[c] = f2bf((v[i][c] - mu) * rs * gamma[col + c] + beta[col + c]);
    *(ushort4v*)(xn + (size_t)row * D_MODEL + col) = o;
  }
}

// ====== qkv GEMM 128x128, BK=32, 3 bufs, 3 blocks/CU, PIPELINED FRAGS ======
// 16x16x32 MFMA (R8 conflict-free swizzle). Tile t's fragments are read one
// tile EARLY (during tile t-1's slot) so MM(t) has zero lgkm stall.
// GATEP = vmcnt gate + lgkmcnt(0) + barrier: after it, all waves' prior
// ds_reads executed -> staging into a consumed buffer is race-free.
// Pair (t,t+1): GATEP(4)[proves t+1] stage(t+3->buf t%3) read(t+1) MM(t) |
// GATEP(4)[proves t+2] stage(t+4->buf (t+1)%3) read(t+2) MM(t+1).
// Epilogue: Q row-major (elu+1); K/V -> blocked [lblk][h][d][l 128].
__global__ __launch_bounds__(256, 3) void gemm_qkv_p_kernel(
    const unsigned short* __restrict__ A, const unsigned short* __restrict__ Bt,
    unsigned short* __restrict__ qb, unsigned short* __restrict__ kT,
    unsigned short* __restrict__ vT) {
  __shared__ unsigned short As[3 * 4096];  // [buf][128][32]
  __shared__ unsigned short Bs[3 * 4096];
  const int K = D_MODEL, nbn = 18, NKT = 24;
  int nwg = gridDim.x, id = blockIdx.x;
  int q8 = nwg >> 3;
  int wg = (id & 7) * q8 + (id >> 3);
  int bm = wg / nbn, bn = wg % nbn;

  const int lane = threadIdx.x & 63, wid = threadIdx.x >> 6;
  const int wm = wid >> 1, wn = wid & 1;
  const int l15 = lane & 15, hi = lane >> 4;
  const int colS = (hi ^ ((l15 >> 1) & 3)) << 3;
  const int srow = lane >> 2;
  const int scol = ((lane & 3) ^ ((lane >> 3) & 3)) << 3;

  const unsigned short* a0 = A  + (size_t)(bm * 128 +      wid * 16 + srow) * K + scol;
  const unsigned short* a1 = A  + (size_t)(bm * 128 + 64 + wid * 16 + srow) * K + scol;
  const unsigned short* b0 = Bt + (size_t)(bn * 128 +      wid * 16 + srow) * K + scol;
  const unsigned short* b1 = Bt + (size_t)(bn * 128 + 64 + wid * 16 + srow) * K + scol;
  auto stage = [&](int buf, int kt) {
    GLOBAL_LDS16(a0 + kt * 32, &As[buf * 4096 +        wid * 512]);
    GLOBAL_LDS16(a1 + kt * 32, &As[buf * 4096 + 2048 + wid * 512]);
    GLOBAL_LDS16(b0 + kt * 32, &Bs[buf * 4096 +        wid * 512]);
    GLOBAL_LDS16(b1 + kt * 32, &Bs[buf * 4096 + 2048 + wid * 512]);
  };

  f32x4 acc[4][4];
  #pragma unroll
  for (int i = 0; i < 4; ++i)
    #pragma unroll
    for (int j = 0; j < 4; ++j) acc[i][j] = (f32x4){0.f, 0.f, 0.f, 0.f};

  bf16x8 afA[4], bvA[4], afB[4], bvB[4];

#define READF(BUF, AF, BV) do { int _o = (BUF) * 4096; \
    _Pragma("unroll") for (int mf = 0; mf < 4; ++mf) \
      AF[mf] = *(const bf16x8*)&As[_o + (wm * 64 + mf * 16 + l15) * 32 + colS]; \
    _Pragma("unroll") for (int nf = 0; nf < 4; ++nf) \
      BV[nf] = *(const bf16x8*)&Bs[_o + (wn * 64 + nf * 16 + l15) * 32 + colS]; \
  } while (0)
#define MMX(AF, BV) do { __builtin_amdgcn_s_setprio(1); \
    _Pragma("unroll") for (int mf = 0; mf < 4; ++mf) \
      _Pragma("unroll") for (int nf = 0; nf < 4; ++nf) \
        acc[mf][nf] = __builtin_amdgcn_mfma_f32_16x16x32_bf16( \
            AF[mf], BV[nf], acc[mf][nf], 0, 0, 0); \
    __builtin_amdgcn_s_setprio(0); \
  } while (0)

  // Prologue: 3 tiles staged (12 loads); prove tile 0, pre-read its frags.
  stage(0, 0); stage(1, 1); stage(2, 2);
  GATEP(8);
  READF(0, afA, bvA);

  #pragma unroll
  for (int i = 0; i < 11; ++i) {        // pairs t=2i: tiles 0..21
    int t = 2 * i;
    GATEP(4);                            // proves t+1; all prior reads executed
    stage(t % 3, t + 3);                 // buf of tile t (in regs) - safe
    READF((t + 1) % 3, afB, bvB);
    MMX(afA, bvA);                       // tile t, zero lgkm stall
    GATEP(4);                            // proves t+2; drains fB reads
    if (i < 10) stage((t + 1) % 3, t + 4);
    READF((t + 2) % 3, afA, bvA);
    MMX(afB, bvB);                       // tile t+1
  }
  // Tail: fA = tile 22; tile 23 staged, not yet proven.
  GATEP(0);
  READF(2, afB, bvB);                    // 23 % 3 = 2
  MMX(afA, bvA);                         // tile 22
  MMX(afB, bvB);                         // tile 23
#undef READF
#undef MMX

  // Epilogue: block-uniform Q / K / V routing (16x16 C layout, blocked K/V)
  int r0 = bm * 128 + wm * 64, c0 = bn * 128 + wn * 64;
  if (bn < 6) {
    #pragma unroll
    for (int mf = 0; mf < 4; ++mf)
      #pragma unroll
      for (int nf = 0; nf < 4; ++nf) {
        int col = c0 + nf * 16 + l15;
        #pragma unroll
        for (int r = 0; r < 4; ++r) {
          int row = r0 + mf * 16 + hi * 4 + r;
          float v = acc[mf][nf][r];
          v = (v > 0.f) ? v + 1.f : __expf(v);          // elu(x)+1
          qb[(size_t)row * D_MODEL + col] = f2bf(v);
        }
      }
  } else {
    const bool isK = (bn < 12);
    unsigned short* T = isK ? kT : vT;
    int cbase = c0 - (isK ? 768 : 1536);
    #pragma unroll
    for (int mf = 0; mf < 4; ++mf) {
      int ll = wm * 64 + mf * 16 + hi * 4;   // local l within 128-row block
      #pragma unroll
      for (int nf = 0; nf < 4; ++nf) {
        int cc = cbase + nf * 16 + l15;
        int h = cc / 96, d = cc - h * 96;
        ushort4v pk;
        #pragma unroll
        for (int r = 0; r < 4; ++r) {
          float v = acc[mf][nf][r];
          if (isK) v = (v > 0.f) ? v + 1.f : __expf(v);  // elu(x)+1
          pk[r] = f2bf(v);
        }
        *(ushort4v*)&T[(((size_t)bm * 8 + h) * 96 + d) * 128 + ll] = pk;
      }
    }
  }
}

// ======== out GEMM 128x128, BK=32, 4 waves, 3 buffers -> 3 blocks/CU ========
__global__ __launch_bounds__(256, 3) void gemm_out_kernel(
    const unsigned short* __restrict__ A, const unsigned short* __restrict__ Bt,
    const float* __restrict__ resid, float* __restrict__ Cf) {
  __shared__ unsigned short As[3 * 4096];  // [buf][128][32]
  __shared__ unsigned short Bs[3 * 4096];
  const int K = D_MODEL, nbn = 6;          // N=768
  int nwg = gridDim.x, id = blockIdx.x;
  int q8 = nwg >> 3;
  int wg = (id & 7) * q8 + (id >> 3);
  int bm = wg / nbn, bn = wg % nbn;

  const int lane = threadIdx.x & 63, wid = threadIdx.x >> 6;
  const int wm = wid >> 1, wn = wid & 1;
  const int l15 = lane & 15, hi = lane >> 4;
  const int colS = (hi ^ ((l15 >> 1) & 3)) << 3;
  const int srow = lane >> 2;
  const int scol = ((lane & 3) ^ ((lane >> 3) & 3)) << 3;

  const unsigned short* a0 = A  + (size_t)(bm * 128 +      wid * 16 + srow) * K + scol;
  const unsigned short* a1 = A  + (size_t)(bm * 128 + 64 + wid * 16 + srow) * K + scol;
  const unsigned short* b0 = Bt + (size_t)(bn * 128 +      wid * 16 + srow) * K + scol;
  const unsigned short* b1 = Bt + (size_t)(bn * 128 + 64 + wid * 16 + srow) * K + scol;
  auto stage = [&](int buf, int kt) {
    GLOBAL_LDS16(a0 + kt * 32, &As[buf * 4096 +        wid * 512]);
    GLOBAL_LDS16(a1 + kt * 32, &As[buf * 4096 + 2048 + wid * 512]);
    GLOBAL_LDS16(b0 + kt * 32, &Bs[buf * 4096 +        wid * 512]);
    GLOBAL_LDS16(b1 + kt * 32, &Bs[buf * 4096 + 2048 + wid * 512]);
  };

  f32x4 acc[4][4];
  #pragma unroll
  for (int i = 0; i < 4; ++i)
    #pragma unroll
    for (int j = 0; j < 4; ++j) acc[i][j] = (f32x4){0.f, 0.f, 0.f, 0.f};

#define HTILE(BUF, STG) do { \
    bf16x8 af[4], bv[4]; \
    _Pragma("unroll") for (int mf = 0; mf < 4; ++mf) \
      af[mf] = *(const bf16x8*)&As[(BUF) * 4096 + (wm * 64 + mf * 16 + l15) * 32 + colS]; \
    _Pragma("unroll") for (int nf = 0; nf < 4; ++nf) \
      bv[nf] = *(const bf16x8*)&Bs[(BUF) * 4096 + (wn * 64 + nf * 16 + l15) * 32 + colS]; \
    STG; \
    __builtin_amdgcn_s_setprio(1); \
    _Pragma("unroll") for (int mf = 0; mf < 4; ++mf) \
      _Pragma("unroll") for (int nf = 0; nf < 4; ++nf) \
        acc[mf][nf] = __builtin_amdgcn_mfma_f32_16x16x32_bf16( \
            af[mf], bv[nf], acc[mf][nf], 0, 0, 0); \
    __builtin_amdgcn_s_setprio(0); \
  } while (0)

  stage(0, 0); stage(1, 1);
  for (int it = 0; it < 7; ++it) {
    int T = 3 * it;
    GATE(4); HTILE(0, stage(2, T + 2));
    GATE(4); HTILE(1, stage(0, T + 3));
    GATE(4); HTILE(2, stage(1, T + 4));
  }
  GATE(4); HTILE(0, stage(2, 23));
  GATE(4); HTILE(1, {});
  GATE(0); HTILE(2, {});
#undef HTILE

  int r0 = bm * 128 + wm * 64, c0 = bn * 128 + wn * 64;
  #pragma unroll
  for (int mf = 0; mf < 4; ++mf)
    #pragma unroll
    for (int nf = 0; nf < 4; ++nf) {
      int col = c0 + nf * 16 + l15;
      #pragma unroll
      for (int r = 0; r < 4; ++r) {
        int row = r0 + mf * 16 + hi * 4 + r;
        Cf[(size_t)row * D_MODEL + col] =
            acc[mf][nf][r] + resid[(size_t)row * D_MODEL + col];
      }
    }
}

// ======== kv aggregation: blocked kT/vT staging + phantom ones-row ======
__global__ __launch_bounds__(256) void kvagg2_kernel(
    const unsigned short* __restrict__ kT, const unsigned short* __restrict__ vT,
    float* __restrict__ kvp) {
  __shared__ unsigned short KTs[3 * 6144];   // [buf][96][64]
  __shared__ unsigned short VTs[3 * 8192];   // [buf][128][64]
  int bh = blockIdx.x >> 2, chunk = blockIdx.x & 3;
  int tid = threadIdx.x;
  int lane = tid & 63, wid = tid >> 6;
  int l15 = lane & 15, hi = lane >> 4;

  #pragma unroll
  for (int i = 0; i < 3; ++i) {
    int s = i * 256 + tid;
    int buf = s >> 8, r = 96 + ((s >> 3) & 31), sl = s & 7;
    unsigned short val = (r == 96) ? (unsigned short)0x3F80 : (unsigned short)0;
    ushort8 v8 = {val, val, val, val, val, val, val, val};
    *(ushort8*)&VTs[buf * 8192 + r * 64 + sl * 8] = v8;
  }
  __syncthreads();

  const int b = bh >> 3, h = bh & 7;
  auto stage = [&](int buf, int t) {
    #pragma unroll
    for (int i = 0; i < 3; ++i) {
      int sidx = i * 256 + tid;
      int row = sidx >> 3;                        // d
      int L = (sidx & 7) ^ (row & 7);
      size_t g = ((((size_t)b * 32 + chunk * 8 + (t >> 1)) * 8 + h) * 96 + row) * 128
               + (t & 1) * 64 + L * 8;
      GLOBAL_LDS16(kT + g, &KTs[buf * 6144 + (i * 256 + wid * 64) * 8]);
      GLOBAL_LDS16(vT + g, &VTs[buf * 8192 + (i * 256 + wid * 64) * 8]);
    }
  };

  f32x4 acc[6][2];
  #pragma unroll
  for (int i = 0; i < 6; ++i)
    #pragma unroll
    for (int j = 0; j < 2; ++j) acc[i][j] = (f32x4){0.f, 0.f, 0.f, 0.f};

#define KVTILE(BUF) do { \
    _Pragma("unroll") for (int kq = 0; kq < 2; ++kq) { \
      bf16x8 af[6], bv[2]; \
      _Pragma("unroll") for (int mf = 0; mf < 6; ++mf) { \
        int row = mf * 16 + l15; \
        af[mf] = *(const bf16x8*)&KTs[(BUF) * 6144 + row * 64 + ((kq * 4 + hi) ^ (row & 7)) * 8]; } \
      _Pragma("unroll") for (int nf = 0; nf < 2; ++nf) { \
        int row = wid * 32 + nf * 16 + l15; \
        bv[nf] = *(const bf16x8*)&VTs[(BUF) * 8192 + row * 64 + ((kq * 4 + hi) ^ (row & 7)) * 8]; } \
      __builtin_amdgcn_s_setprio(1); \
      _Pragma("unroll") for (int mf = 0; mf < 6; ++mf) \
        _Pragma("unroll") for (int nf = 0; nf < 2; ++nf) \
          acc[mf][nf] = __builtin_amdgcn_mfma_f32_16x16x32_bf16( \
              af[mf], bv[nf], acc[mf][nf], 0, 0, 0); \
      __builtin_amdgcn_s_setprio(0); \
    } } while (0)

  stage(0, 0); stage(1, 1);
  for (int t = 0; t < 14; ++t) {
    stage((t + 2) % 3, t + 2);
    GATE(12);
    KVTILE(t % 3);
  }
  GATE(6); KVTILE(2);
  GATE(0); KVTILE(0);
#undef KVTILE

  float* outp = kvp + ((size_t)bh * 4 + chunk) * (96 * 112);
  #pragma unroll
  for (int nf = 0; nf < 2; ++nf) {
    int e = wid * 32 + nf * 16 + l15;
    if (e < 112) {
      #pragma unroll
      for (int mf = 0; mf < 6; ++mf)
        #pragma unroll
        for (int r = 0; r < 4; ++r) {
          int d = mf * 16 + hi * 4 + r;
          outp[d * 112 + e] = acc[mf][nf][r];
        }
    }
  }
}

// ---------------- reduce 4 partials -> kvT bf16 [64][112][96] ----------------
__global__ __launch_bounds__(256) void kvreduce_kernel(
    const float* __restrict__ kvp, unsigned short* __restrict__ kvTo) {
  int idx = blockIdx.x * 256 + threadIdx.x;
  if (idx >= 64 * 112 * 96) return;
  int d = idx % 96;
  int e = (idx / 96) % 112;
  int bh = idx / (96 * 112);
  float s = 0.f;
  #pragma unroll
  for (int c = 0; c < 4; ++c)
    s += kvp[(((size_t)bh * 4 + c) * 96 + d) * 112 + e];
  kvTo[idx] = f2bf(s);
}

// ---------------- readout: q row-major in qb [32768][768] ----------------
__global__ __launch_bounds__(256) void readout_kernel(
    const unsigned short* __restrict__ qb, const unsigned short* __restrict__ kvT,
    unsigned short* __restrict__ attn) {
  __shared__ unsigned short Qs[128][104];
  __shared__ unsigned short Ks[112][104];
  int bh = blockIdx.x >> 5, lc = blockIdx.x & 31;
  int b = bh >> 3, h = bh & 7;
  int l0 = lc * 128;
  int wave = threadIdx.x >> 6, lane = threadIdx.x & 63;
  #pragma unroll
  for (int i = 0; i < 6; ++i) {
    int idx = i * 256 + threadIdx.x;
    int l = idx / 12, oc = idx % 12;
    size_t g = ((size_t)b * SEQ + l0 + l) * D_MODEL + h * DH + oc * 8;
    *(ushort8*)&Qs[l][oc * 8] = *(const ushort8*)(qb + g);
  }
  const unsigned short* kvbh = kvT + (size_t)bh * 112 * 96;
  #pragma unroll
  for (int i = 0; i < 6; ++i) {
    int idx = i * 256 + threadIdx.x;
    if (idx < 1344) {
      int e = idx / 12, oc = idx % 12;
      *(ushort8*)&Ks[e][oc * 8] = *(const ushort8*)(kvbh + e * 96 + oc * 8);
    }
  }
  __syncthreads();
  f32x4 acc[2][7];
  #pragma unroll
  for (int i = 0; i < 2; ++i)
    #pragma unroll
    for (int j = 0; j < 7; ++j) acc[i][j] = (f32x4){0.f, 0.f, 0.f, 0.f};
  #pragma unroll
  for (int kq = 0; kq < 3; ++kq) {
    int k0 = kq * 32 + (lane >> 4) * 8;
    bf16x8 af[2], bfv[7];
    #pragma unroll
    for (int i = 0; i < 2; ++i) af[i]  = *(const bf16x8*)&Qs[wave * 32 + i * 16 + (lane & 15)][k0];
    #pragma unroll
    for (int j = 0; j < 7; ++j) bfv[j] = *(const bf16x8*)&Ks[j * 16 + (lane & 15)][k0];
    #pragma unroll
    for (int i = 0; i < 2; ++i)
      #pragma unroll
      for (int j = 0; j < 7; ++j)
        acc[i][j] = __builtin_amdgcn_mfma_f32_16x16x32_bf16(af[i], bfv[j], acc[i][j], 0, 0, 0);
  }
  int g4 = lane >> 4;
  #pragma unroll
  for (int i = 0; i < 2; ++i) {
    #pragma unroll
    for (int r = 0; r < 4; ++r) {
      float nv = __shfl(acc[i][6][r], lane & 48, 64);   // col 96 = normalizer
      float inv = 1.f / fmaxf(nv, 1e-6f);
      size_t orow = (size_t)b * SEQ + l0 + wave * 32 + i * 16 + g4 * 4 + r;
      #pragma unroll
      for (int j = 0; j < 6; ++j) {
        int col = h * DH + j * 16 + (lane & 15);
        attn[orow * D_MODEL + col] = f2bf(acc[i][j][r] * inv);
      }
    }
  }
}

extern "C" void kernel_launch(void* const* d_in, const int* in_sizes, int n_in,
                              void* d_out, int out_size, void* d_ws, size_t ws_size,
                              hipStream_t stream) {
  const float* x     = (const float*)d_in[0];
  const float* gamma = (const float*)d_in[1];
  const float* beta  = (const float*)d_in[2];
  const float* w_qkv = (const float*)d_in[3];
  const float* w_out = (const float*)d_in[4];
  float* out = (float*)d_out;

  char* ws = (char*)d_ws;
  size_t off = 0;
  auto alloc = [&](size_t bytes) -> void* {
    void* p = ws + off; off += (bytes + 255) & ~(size_t)255; return p;
  };
  unsigned short* xn    = (unsigned short*)alloc((size_t)ROWS * D_MODEL * 2);  // reused as attn
  unsigned short* qb    = (unsigned short*)alloc((size_t)ROWS * D_MODEL * 2);
  unsigned short* kTb   = (unsigned short*)alloc((size_t)64 * 96 * SEQ * 2);
  unsigned short* vTb   = (unsigned short*)alloc((size_t)64 * 96 * SEQ * 2);
  unsigned short* wqkvT = (unsigned short*)alloc((size_t)N3 * D_MODEL * 2);
  unsigned short* woutT = (unsigned short*)alloc((size_t)D_MODEL * D_MODEL * 2);
  float* kvp            = (float*)alloc((size_t)256 * 96 * 112 * 4);
  unsigned short* kvT   = (unsigned short*)alloc((size_t)64 * 112 * 96 * 2);

  transpose2_kernel<<<dim3(96, 24), 256, 0, stream>>>(w_qkv, w_out, wqkvT, woutT);
  ln_kernel<<<ROWS / 4, 256, 0, stream>>>(x, gamma, beta, xn);
  gemm_qkv_p_kernel<<<(ROWS / 128) * (N3 / 128), 256, 0, stream>>>(xn, wqkvT, qb, kTb, vTb);
  kvagg2_kernel<<<256, 256, 0, stream>>>(kTb, vTb, kvp);
  kvreduce_kernel<<<(64 * 112 * 96 + 255) / 256, 256, 0, stream>>>(kvp, kvT);
  readout_kernel<<<2048, 256, 0, stream>>>(qb, kvT, xn);  // attn overwrites xn
  gemm_out_kernel<<<(ROWS / 128) * (D_MODEL / 128), 256, 0, stream>>>(xn, woutT, x, out);
}

// Round 11
// 325.969 us; speedup vs baseline: 1.0483x; 1.0060x over previous
//
#include <hip/hip_runtime.h>
#include <stdint.h>

#define D_MODEL 768
#define N3      2304
#define NHEAD   8
#define DH      96
#define BATCH   8
#define SEQ     4096
#define ROWS    (BATCH*SEQ)   // 32768
#define LN_EPS  1e-5f

typedef __attribute__((ext_vector_type(8))) __bf16 bf16x8;
typedef __attribute__((ext_vector_type(4))) float f32x4;
typedef __attribute__((ext_vector_type(8))) unsigned short ushort8;
typedef __attribute__((ext_vector_type(4))) unsigned short ushort4v;

__device__ __forceinline__ unsigned short f2bf(float f) {
  union { float f; unsigned int u; } v; v.f = f;
  unsigned int r = v.u + 0x7FFFu + ((v.u >> 16) & 1u);
  return (unsigned short)(r >> 16);
}
__device__ __forceinline__ float bf2f(unsigned short u) {
  union { unsigned int u; float f; } v; v.u = ((unsigned int)u) << 16;
  return v.f;
}

#define GLOBAL_LDS16(src, dst) \
  __builtin_amdgcn_global_load_lds((const __attribute__((address_space(1))) void*)(src), \
                                   (__attribute__((address_space(3))) void*)(dst), 16, 0, 0)

#define GATE(n) do { asm volatile("s_waitcnt vmcnt(" #n ")" ::: "memory"); \
                     __builtin_amdgcn_s_barrier(); asm volatile("" ::: "memory"); } while (0)

// ---------------- merged transpose + cast fp32[R][C] -> bf16[C][R] ----------------
__global__ __launch_bounds__(256) void transpose2_kernel(
    const float* __restrict__ wqkv, const float* __restrict__ wout,
    unsigned short* __restrict__ wqkvT, unsigned short* __restrict__ woutT) {
  __shared__ float tile[32][33];
  int bx = blockIdx.x;
  const float* in; unsigned short* out; int C, c0;
  if (bx < 72) { in = wqkv; out = wqkvT; C = N3;      c0 = bx * 32; }
  else         { in = wout; out = woutT; C = D_MODEL; c0 = (bx - 72) * 32; }
  int r0 = blockIdx.y * 32;
  int tx = threadIdx.x & 31, ty = threadIdx.x >> 5;
  #pragma unroll
  for (int i = ty; i < 32; i += 8)
    tile[i][tx] = in[(size_t)(r0 + i) * C + c0 + tx];
  __syncthreads();
  #pragma unroll
  for (int i = ty; i < 32; i += 8)
    out[(size_t)(c0 + i) * D_MODEL + r0 + tx] = f2bf(tile[tx][i]);
}

// ---------------- LayerNorm: fp32 in -> bf16 out, one wave per row ----------------
__global__ __launch_bounds__(256) void ln_kernel(
    const float* __restrict__ x, const float* __restrict__ gamma,
    const float* __restrict__ beta, unsigned short* __restrict__ xn) {
  int wave = threadIdx.x >> 6, lane = threadIdx.x & 63;
  int row = blockIdx.x * 4 + wave;
  const float* xr = x + (size_t)row * D_MODEL;
  f32x4 v[3];
  float s = 0.f, sq = 0.f;
  #pragma unroll
  for (int i = 0; i < 3; ++i) {
    v[i] = *(const f32x4*)(xr + (i * 64 + lane) * 4);
    #pragma unroll
    for (int c = 0; c < 4; ++c) { s += v[i][c]; sq += v[i][c] * v[i][c]; }
  }
  #pragma unroll
  for (int o = 32; o; o >>= 1) {
    s  += __shfl_xor(s, o, 64);
    sq += __shfl_xor(sq, o, 64);
  }
  float mu  = s * (1.f / 768.f);
  float var = sq * (1.f / 768.f) - mu * mu;
  float rs  = rsqrtf(var + LN_EPS);
  #pragma unroll
  for (int i = 0; i < 3; ++i) {
    int col = (i * 64 + lane) * 4;
    ushort4v o;
    #pragma unroll
    for (int c = 0; c < 4; ++c)
      o[c] = f2bf((v[i][c] - mu) * rs * gamma[col + c] + beta[col + c]);
    *(ushort4v*)(xn + (size_t)row * D_MODEL + col) = o;
  }
}

// ====== qkv GEMM 128x256, BK=32, 3 bufs, 2 blocks/CU, 128x64 wave tiles ======
// C = A[32768][768] @ Bt[2304][768]^T. 4 waves (1M x 4N); per-wave out 128x64:
// 8 A-frags + 4 B-frags -> 32 MFMA (12 LDS reads / 32 MFMA = half of R10's
// bytes-per-FLOP; LDS read port was the binding resource).
// Grid 256 bm x 9 bn = 2304 (%8==0). bn 0-2 -> Q row-major (elu+1);
// 3-5 -> K, 6-8 -> V in blocked layout [lblk=bm][h][d][l 128].
// Pipeline (R8-proven): tile T reads buf T%3; stage(T+2)->buf (T-1)%3 (dead);
// GATE(6) at tile top proves T landed (6 loads/wave/tile, FIFO vmcnt);
// tail GATE(6)/GATE(0). Swizzle: phys slot = logical ^ ((row>>1)&3), both sides.
__global__ __launch_bounds__(256, 2) void gemm_qkv_w_kernel(
    const unsigned short* __restrict__ A, const unsigned short* __restrict__ Bt,
    unsigned short* __restrict__ qb, unsigned short* __restrict__ kT,
    unsigned short* __restrict__ vT) {
  __shared__ unsigned short As[3 * 4096];   // [buf][128][32]
  __shared__ unsigned short Bs[3 * 8192];   // [buf][256][32]
  const int K = D_MODEL, nbn = 9;
  int nwg = gridDim.x, id = blockIdx.x;
  int q8 = nwg >> 3;
  int wg = (id & 7) * q8 + (id >> 3);
  int bm = wg / nbn, bn = wg % nbn;

  const int lane = threadIdx.x & 63, wid = threadIdx.x >> 6;
  const int wn = wid;                       // 4 waves across N
  const int l15 = lane & 15, hi = lane >> 4;
  const int colS = (hi ^ ((l15 >> 1) & 3)) << 3;
  const int srow = lane >> 2;
  const int scol = ((lane & 3) ^ ((lane >> 3) & 3)) << 3;

  const unsigned short* a0 = A  + (size_t)(bm * 128 +      wid * 16 + srow) * K + scol;
  const unsigned short* a1 = A  + (size_t)(bm * 128 + 64 + wid * 16 + srow) * K + scol;
  const unsigned short* b0 = Bt + (size_t)(bn * 256 + wid * 64 +      srow) * K + scol;
  const unsigned short* b1 = Bt + (size_t)(bn * 256 + wid * 64 + 16 + srow) * K + scol;
  const unsigned short* b2 = Bt + (size_t)(bn * 256 + wid * 64 + 32 + srow) * K + scol;
  const unsigned short* b3 = Bt + (size_t)(bn * 256 + wid * 64 + 48 + srow) * K + scol;
  auto stage = [&](int buf, int kt) {
    GLOBAL_LDS16(a0 + kt * 32, &As[buf * 4096 +        wid * 512]);
    GLOBAL_LDS16(a1 + kt * 32, &As[buf * 4096 + 2048 + wid * 512]);
    GLOBAL_LDS16(b0 + kt * 32, &Bs[buf * 8192 + wid * 2048]);
    GLOBAL_LDS16(b1 + kt * 32, &Bs[buf * 8192 + wid * 2048 + 512]);
    GLOBAL_LDS16(b2 + kt * 32, &Bs[buf * 8192 + wid * 2048 + 1024]);
    GLOBAL_LDS16(b3 + kt * 32, &Bs[buf * 8192 + wid * 2048 + 1536]);
  };

  f32x4 acc[8][4];   // rows mf*16+hi*4+r (128), cols wn*64+nf*16+l15
  #pragma unroll
  for (int i = 0; i < 8; ++i)
    #pragma unroll
    for (int j = 0; j < 4; ++j) acc[i][j] = (f32x4){0.f, 0.f, 0.f, 0.f};

#define QTILE(BUF, STG) do { \
    bf16x8 af[8], bv[4]; \
    _Pragma("unroll") for (int mf = 0; mf < 8; ++mf) \
      af[mf] = *(const bf16x8*)&As[(BUF) * 4096 + (mf * 16 + l15) * 32 + colS]; \
    _Pragma("unroll") for (int nf = 0; nf < 4; ++nf) \
      bv[nf] = *(const bf16x8*)&Bs[(BUF) * 8192 + (wn * 64 + nf * 16 + l15) * 32 + colS]; \
    STG; \
    __builtin_amdgcn_s_setprio(1); \
    _Pragma("unroll") for (int mf = 0; mf < 8; ++mf) \
      _Pragma("unroll") for (int nf = 0; nf < 4; ++nf) \
        acc[mf][nf] = __builtin_amdgcn_mfma_f32_16x16x32_bf16( \
            af[mf], bv[nf], acc[mf][nf], 0, 0, 0); \
    __builtin_amdgcn_s_setprio(0); \
  } while (0)

  stage(0, 0); stage(1, 1);
  for (int it = 0; it < 7; ++it) {
    int T = 3 * it;
    GATE(6); QTILE(0, stage(2, T + 2));
    GATE(6); QTILE(1, stage(0, T + 3));
    GATE(6); QTILE(2, stage(1, T + 4));
  }
  GATE(6); QTILE(0, stage(2, 23));
  GATE(6); QTILE(1, {});
  GATE(0); QTILE(2, {});
#undef QTILE

  // Epilogue: block-uniform Q / K / V routing
  int r0 = bm * 128, c0 = bn * 256 + wn * 64;
  if (bn < 3) {
    #pragma unroll
    for (int mf = 0; mf < 8; ++mf)
      #pragma unroll
      for (int nf = 0; nf < 4; ++nf) {
        int col = c0 + nf * 16 + l15;
        #pragma unroll
        for (int r = 0; r < 4; ++r) {
          int row = r0 + mf * 16 + hi * 4 + r;
          float v = acc[mf][nf][r];
          v = (v > 0.f) ? v + 1.f : __expf(v);          // elu(x)+1
          qb[(size_t)row * D_MODEL + col] = f2bf(v);
        }
      }
  } else {
    const bool isK = (bn < 6);
    unsigned short* T = isK ? kT : vT;
    int cbase = c0 - (isK ? 768 : 1536);
    #pragma unroll
    for (int mf = 0; mf < 8; ++mf) {
      int ll = mf * 16 + hi * 4;             // local l within 128-row block
      #pragma unroll
      for (int nf = 0; nf < 4; ++nf) {
        int cc = cbase + nf * 16 + l15;
        int h = cc / 96, d = cc - h * 96;
        ushort4v pk;
        #pragma unroll
        for (int r = 0; r < 4; ++r) {
          float v = acc[mf][nf][r];
          if (isK) v = (v > 0.f) ? v + 1.f : __expf(v);  // elu(x)+1
          pk[r] = f2bf(v);
        }
        *(ushort4v*)&T[(((size_t)bm * 8 + h) * 96 + d) * 128 + ll] = pk;
      }
    }
  }
}

// ======== out GEMM 128x128, BK=32, 4 waves, 3 buffers -> 3 blocks/CU ========
__global__ __launch_bounds__(256, 3) void gemm_out_kernel(
    const unsigned short* __restrict__ A, const unsigned short* __restrict__ Bt,
    const float* __restrict__ resid, float* __restrict__ Cf) {
  __shared__ unsigned short As[3 * 4096];  // [buf][128][32]
  __shared__ unsigned short Bs[3 * 4096];
  const int K = D_MODEL, nbn = 6;          // N=768
  int nwg = gridDim.x, id = blockIdx.x;
  int q8 = nwg >> 3;
  int wg = (id & 7) * q8 + (id >> 3);
  int bm = wg / nbn, bn = wg % nbn;

  const int lane = threadIdx.x & 63, wid = threadIdx.x >> 6;
  const int wm = wid >> 1, wn = wid & 1;
  const int l15 = lane & 15, hi = lane >> 4;
  const int colS = (hi ^ ((l15 >> 1) & 3)) << 3;
  const int srow = lane >> 2;
  const int scol = ((lane & 3) ^ ((lane >> 3) & 3)) << 3;

  const unsigned short* a0 = A  + (size_t)(bm * 128 +      wid * 16 + srow) * K + scol;
  const unsigned short* a1 = A  + (size_t)(bm * 128 + 64 + wid * 16 + srow) * K + scol;
  const unsigned short* b0 = Bt + (size_t)(bn * 128 +      wid * 16 + srow) * K + scol;
  const unsigned short* b1 = Bt + (size_t)(bn * 128 + 64 + wid * 16 + srow) * K + scol;
  auto stage = [&](int buf, int kt) {
    GLOBAL_LDS16(a0 + kt * 32, &As[buf * 4096 +        wid * 512]);
    GLOBAL_LDS16(a1 + kt * 32, &As[buf * 4096 + 2048 + wid * 512]);
    GLOBAL_LDS16(b0 + kt * 32, &Bs[buf * 4096 +        wid * 512]);
    GLOBAL_LDS16(b1 + kt * 32, &Bs[buf * 4096 + 2048 + wid * 512]);
  };

  f32x4 acc[4][4];
  #pragma unroll
  for (int i = 0; i < 4; ++i)
    #pragma unroll
    for (int j = 0; j < 4; ++j) acc[i][j] = (f32x4){0.f, 0.f, 0.f, 0.f};

#define HTILE(BUF, STG) do { \
    bf16x8 af[4], bv[4]; \
    _Pragma("unroll") for (int mf = 0; mf < 4; ++mf) \
      af[mf] = *(const bf16x8*)&As[(BUF) * 4096 + (wm * 64 + mf * 16 + l15) * 32 + colS]; \
    _Pragma("unroll") for (int nf = 0; nf < 4; ++nf) \
      bv[nf] = *(const bf16x8*)&Bs[(BUF) * 4096 + (wn * 64 + nf * 16 + l15) * 32 + colS]; \
    STG; \
    __builtin_amdgcn_s_setprio(1); \
    _Pragma("unroll") for (int mf = 0; mf < 4; ++mf) \
      _Pragma("unroll") for (int nf = 0; nf < 4; ++nf) \
        acc[mf][nf] = __builtin_amdgcn_mfma_f32_16x16x32_bf16( \
            af[mf], bv[nf], acc[mf][nf], 0, 0, 0); \
    __builtin_amdgcn_s_setprio(0); \
  } while (0)

  stage(0, 0); stage(1, 1);
  for (int it = 0; it < 7; ++it) {
    int T = 3 * it;
    GATE(4); HTILE(0, stage(2, T + 2));
    GATE(4); HTILE(1, stage(0, T + 3));
    GATE(4); HTILE(2, stage(1, T + 4));
  }
  GATE(4); HTILE(0, stage(2, 23));
  GATE(4); HTILE(1, {});
  GATE(0); HTILE(2, {});
#undef HTILE

  int r0 = bm * 128 + wm * 64, c0 = bn * 128 + wn * 64;
  #pragma unroll
  for (int mf = 0; mf < 4; ++mf)
    #pragma unroll
    for (int nf = 0; nf < 4; ++nf) {
      int col = c0 + nf * 16 + l15;
      #pragma unroll
      for (int r = 0; r < 4; ++r) {
        int row = r0 + mf * 16 + hi * 4 + r;
        Cf[(size_t)row * D_MODEL + col] =
            acc[mf][nf][r] + resid[(size_t)row * D_MODEL + col];
      }
    }
}

// ======== kv aggregation: blocked kT/vT staging + phantom ones-row ======
__global__ __launch_bounds__(256) void kvagg2_kernel(
    const unsigned short* __restrict__ kT, const unsigned short* __restrict__ vT,
    float* __restrict__ kvp) {
  __shared__ unsigned short KTs[3 * 6144];   // [buf][96][64]
  __shared__ unsigned short VTs[3 * 8192];   // [buf][128][64]
  int bh = blockIdx.x >> 2, chunk = blockIdx.x & 3;
  int tid = threadIdx.x;
  int lane = tid & 63, wid = tid >> 6;
  int l15 = lane & 15, hi = lane >> 4;

  #pragma unroll
  for (int i = 0; i < 3; ++i) {
    int s = i * 256 + tid;
    int buf = s >> 8, r = 96 + ((s >> 3) & 31), sl = s & 7;
    unsigned short val = (r == 96) ? (unsigned short)0x3F80 : (unsigned short)0;
    ushort8 v8 = {val, val, val, val, val, val, val, val};
    *(ushort8*)&VTs[buf * 8192 + r * 64 + sl * 8] = v8;
  }
  __syncthreads();

  const int b = bh >> 3, h = bh & 7;
  auto stage = [&](int buf, int t) {
    #pragma unroll
    for (int i = 0; i < 3; ++i) {
      int sidx = i * 256 + tid;
      int row = sidx >> 3;                        // d
      int L = (sidx & 7) ^ (row & 7);
      size_t g = ((((size_t)b * 32 + chunk * 8 + (t >> 1)) * 8 + h) * 96 + row) * 128
               + (t & 1) * 64 + L * 8;
      GLOBAL_LDS16(kT + g, &KTs[buf * 6144 + (i * 256 + wid * 64) * 8]);
      GLOBAL_LDS16(vT + g, &VTs[buf * 8192 + (i * 256 + wid * 64) * 8]);
    }
  };

  f32x4 acc[6][2];
  #pragma unroll
  for (int i = 0; i < 6; ++i)
    #pragma unroll
    for (int j = 0; j < 2; ++j) acc[i][j] = (f32x4){0.f, 0.f, 0.f, 0.f};

#define KVTILE(BUF) do { \
    _Pragma("unroll") for (int kq = 0; kq < 2; ++kq) { \
      bf16x8 af[6], bv[2]; \
      _Pragma("unroll") for (int mf = 0; mf < 6; ++mf) { \
        int row = mf * 16 + l15; \
        af[mf] = *(const bf16x8*)&KTs[(BUF) * 6144 + row * 64 + ((kq * 4 + hi) ^ (row & 7)) * 8]; } \
      _Pragma("unroll") for (int nf = 0; nf < 2; ++nf) { \
        int row = wid * 32 + nf * 16 + l15; \
        bv[nf] = *(const bf16x8*)&VTs[(BUF) * 8192 + row * 64 + ((kq * 4 + hi) ^ (row & 7)) * 8]; } \
      __builtin_amdgcn_s_setprio(1); \
      _Pragma("unroll") for (int mf = 0; mf < 6; ++mf) \
        _Pragma("unroll") for (int nf = 0; nf < 2; ++nf) \
          acc[mf][nf] = __builtin_amdgcn_mfma_f32_16x16x32_bf16( \
              af[mf], bv[nf], acc[mf][nf], 0, 0, 0); \
      __builtin_amdgcn_s_setprio(0); \
    } } while (0)

  stage(0, 0); stage(1, 1);
  for (int t = 0; t < 14; ++t) {
    stage((t + 2) % 3, t + 2);
    GATE(12);
    KVTILE(t % 3);
  }
  GATE(6); KVTILE(2);
  GATE(0); KVTILE(0);
#undef KVTILE

  float* outp = kvp + ((size_t)bh * 4 + chunk) * (96 * 112);
  #pragma unroll
  for (int nf = 0; nf < 2; ++nf) {
    int e = wid * 32 + nf * 16 + l15;
    if (e < 112) {
      #pragma unroll
      for (int mf = 0; mf < 6; ++mf)
        #pragma unroll
        for (int r = 0; r < 4; ++r) {
          int d = mf * 16 + hi * 4 + r;
          outp[d * 112 + e] = acc[mf][nf][r];
        }
    }
  }
}

// ---------------- reduce 4 partials -> kvT bf16 [64][112][96] ----------------
__global__ __launch_bounds__(256) void kvreduce_kernel(
    const float* __restrict__ kvp, unsigned short* __restrict__ kvTo) {
  int idx = blockIdx.x * 256 + threadIdx.x;
  if (idx >= 64 * 112 * 96) return;
  int d = idx % 96;
  int e = (idx / 96) % 112;
  int bh = idx / (96 * 112);
  float s = 0.f;
  #pragma unroll
  for (int c = 0; c < 4; ++c)
    s += kvp[(((size_t)bh * 4 + c) * 96 + d) * 112 + e];
  kvTo[idx] = f2bf(s);
}

// ---------------- readout: q row-major in qb [32768][768] ----------------
__global__ __launch_bounds__(256) void readout_kernel(
    const unsigned short* __restrict__ qb, const unsigned short* __restrict__ kvT,
    unsigned short* __restrict__ attn) {
  __shared__ unsigned short Qs[128][104];
  __shared__ unsigned short Ks[112][104];
  int bh = blockIdx.x >> 5, lc = blockIdx.x & 31;
  int b = bh >> 3, h = bh & 7;
  int l0 = lc * 128;
  int wave = threadIdx.x >> 6, lane = threadIdx.x & 63;
  #pragma unroll
  for (int i = 0; i < 6; ++i) {
    int idx = i * 256 + threadIdx.x;
    int l = idx / 12, oc = idx % 12;
    size_t g = ((size_t)b * SEQ + l0 + l) * D_MODEL + h * DH + oc * 8;
    *(ushort8*)&Qs[l][oc * 8] = *(const ushort8*)(qb + g);
  }
  const unsigned short* kvbh = kvT + (size_t)bh * 112 * 96;
  #pragma unroll
  for (int i = 0; i < 6; ++i) {
    int idx = i * 256 + threadIdx.x;
    if (idx < 1344) {
      int e = idx / 12, oc = idx % 12;
      *(ushort8*)&Ks[e][oc * 8] = *(const ushort8*)(kvbh + e * 96 + oc * 8);
    }
  }
  __syncthreads();
  f32x4 acc[2][7];
  #pragma unroll
  for (int i = 0; i < 2; ++i)
    #pragma unroll
    for (int j = 0; j < 7; ++j) acc[i][j] = (f32x4){0.f, 0.f, 0.f, 0.f};
  #pragma unroll
  for (int kq = 0; kq < 3; ++kq) {
    int k0 = kq * 32 + (lane >> 4) * 8;
    bf16x8 af[2], bfv[7];
    #pragma unroll
    for (int i = 0; i < 2; ++i) af[i]  = *(const bf16x8*)&Qs[wave * 32 + i * 16 + (lane & 15)][k0];
    #pragma unroll
    for (int j = 0; j < 7; ++j) bfv[j] = *(const bf16x8*)&Ks[j * 16 + (lane & 15)][k0];
    #pragma unroll
    for (int i = 0; i < 2; ++i)
      #pragma unroll
      for (int j = 0; j < 7; ++j)
        acc[i][j] = __builtin_amdgcn_mfma_f32_16x16x32_bf16(af[i], bfv[j], acc[i][j], 0, 0, 0);
  }
  int g4 = lane >> 4;
  #pragma unroll
  for (int i = 0; i < 2; ++i) {
    #pragma unroll
    for (int r = 0; r < 4; ++r) {
      float nv = __shfl(acc[i][6][r], lane & 48, 64);   // col 96 = normalizer
      float inv = 1.f / fmaxf(nv, 1e-6f);
      size_t orow = (size_t)b * SEQ + l0 + wave * 32 + i * 16 + g4 * 4 + r;
      #pragma unroll
      for (int j = 0; j < 6; ++j) {
        int col = h * DH + j * 16 + (lane & 15);
        attn[orow * D_MODEL + col] = f2bf(acc[i][j][r] * inv);
      }
    }
  }
}

extern "C" void kernel_launch(void* const* d_in, const int* in_sizes, int n_in,
                              void* d_out, int out_size, void* d_ws, size_t ws_size,
                              hipStream_t stream) {
  const float* x     = (const float*)d_in[0];
  const float* gamma = (const float*)d_in[1];
  const float* beta  = (const float*)d_in[2];
  const float* w_qkv = (const float*)d_in[3];
  const float* w_out = (const float*)d_in[4];
  float* out = (float*)d_out;

  char* ws = (char*)d_ws;
  size_t off = 0;
  auto alloc = [&](size_t bytes) -> void* {
    void* p = ws + off; off += (bytes + 255) & ~(size_t)255; return p;
  };
  unsigned short* xn    = (unsigned short*)alloc((size_t)ROWS * D_MODEL * 2);  // reused as attn
  unsigned short* qb    = (unsigned short*)alloc((size_t)ROWS * D_MODEL * 2);
  unsigned short* kTb   = (unsigned short*)alloc((size_t)64 * 96 * SEQ * 2);
  unsigned short* vTb   = (unsigned short*)alloc((size_t)64 * 96 * SEQ * 2);
  unsigned short* wqkvT = (unsigned short*)alloc((size_t)N3 * D_MODEL * 2);
  unsigned short* woutT = (unsigned short*)alloc((size_t)D_MODEL * D_MODEL * 2);
  float* kvp            = (float*)alloc((size_t)256 * 96 * 112 * 4);
  unsigned short* kvT   = (unsigned short*)alloc((size_t)64 * 112 * 96 * 2);

  transpose2_kernel<<<dim3(96, 24), 256, 0, stream>>>(w_qkv, w_out, wqkvT, woutT);
  ln_kernel<<<ROWS / 4, 256, 0, stream>>>(x, gamma, beta, xn);
  gemm_qkv_w_kernel<<<(ROWS / 128) * (N3 / 256), 256, 0, stream>>>(xn, wqkvT, qb, kTb, vTb);
  kvagg2_kernel<<<256, 256, 0, stream>>>(kTb, vTb, kvp);
  kvreduce_kernel<<<(64 * 112 * 96 + 255) / 256, 256, 0, stream>>>(kvp, kvT);
  readout_kernel<<<2048, 256, 0, stream>>>(qb, kvT, xn);  // attn overwrites xn
  gemm_out_kernel<<<(ROWS / 128) * (D_MODEL / 128), 256, 0, stream>>>(xn, woutT, x, out);
}